// Round 7
// baseline (116.053 us; speedup 1.0000x reference)
//
#include <hip/hip_runtime.h>
#include <cstdint>
#include <cstddef>

// NetGrad J = W5 D4 W4 D3 W3 D2 W2 D1 W1, output [B,3,64].
// Single fused kernel per 16-sample block: fwd chain (H ping-pong in LDS,
// G1..G4 in registers, same lane mapping as bwd consumer) then bwd chain
// (48-row C in LDS, row layout o*16+s). MFMA f16 hi/lo split (hh+hl+lh).
// Round 7: sched_group_barrier-pinned k-loops (T19) + ring-3 register
// prefetch of global B-fragments (depth 2), ring-2 LDS A-prefetch in fwd.

typedef _Float16 half_t;
typedef __attribute__((ext_vector_type(8))) _Float16 half8;
typedef __attribute__((ext_vector_type(4))) float f32x4;

#define MFMA16(a, b, c) __builtin_amdgcn_mfma_f32_16x16x32_f16(a, b, c, 0, 0, 0)
#define SGB(mask, n) __builtin_amdgcn_sched_group_barrier((mask), (n), 0)
// masks: VALU=0x2 MFMA=0x8 VMEM_READ=0x20 DS_READ=0x100 DS_WRITE=0x200

constexpr int Bsz = 8192;
constexpr int D   = 256;
constexpr int LDA = 264;          // LDS row stride in halves (528 B)

// ---------------- prep: split (native) + transpose-split all weights ----------------
__global__ __launch_bounds__(256)
void prep_split(const float* __restrict__ W1, const float* __restrict__ W2,
                const float* __restrict__ W3, const float* __restrict__ W4,
                half_t* W1h, half_t* W1l, half_t* T1h, half_t* T1l,
                half_t* W2h, half_t* W2l, half_t* T2h, half_t* T2l,
                half_t* W3h, half_t* W3l, half_t* T3h, half_t* T3l,
                half_t* W4h, half_t* W4l, half_t* T4h, half_t* T4l)
{
    __shared__ float tile[32][33];
    const int bid = blockIdx.x;
    const float* src; half_t *sh, *sl, *th, *tl; int C, bx, by;
    if (bid < 16) {
        src = W1; sh = W1h; sl = W1l; th = T1h; tl = T1l;
        C = 64; bx = bid & 1; by = bid >> 1;
    } else {
        const int q = bid - 16, j = q >> 6, lo = q & 63;
        bx = lo & 7; by = lo >> 3; C = 256;
        if (j == 0)      { src = W2; sh = W2h; sl = W2l; th = T2h; tl = T2l; }
        else if (j == 1) { src = W3; sh = W3h; sl = W3l; th = T3h; tl = T3l; }
        else             { src = W4; sh = W4h; sl = W4l; th = T4h; tl = T4l; }
    }
    const int R = 256;
    const int tx = threadIdx.x & 31, ty = threadIdx.x >> 5;
    #pragma unroll
    for (int i = 0; i < 32; i += 8) {
        const size_t o = (size_t)(by * 32 + ty + i) * C + bx * 32 + tx;
        const float v = src[o];
        tile[ty + i][tx] = v;
        const half_t h = (half_t)v;
        sh[o] = h; sl[o] = (half_t)(v - (float)h);
    }
    __syncthreads();
    #pragma unroll
    for (int i = 0; i < 32; i += 8) {
        const float v = tile[tx][ty + i];
        const half_t h = (half_t)v;
        const size_t o = (size_t)(bx * 32 + ty + i) * R + by * 32 + tx;
        th[o] = h; tl[o] = (half_t)(v - (float)h);
    }
}

// ---------------- fwd layer: pre = A @ W^T + b; G -> regs; H' = elu -> LDS nxt ----------------
// Ring-3 B prefetch (depth 2, global) + ring-2 A prefetch (depth 1, LDS),
// emission pinned per k-step with sched_group_barrier.
template<int K, bool WRITE_H>
__device__ __forceinline__
void fwd_layer(const half_t* __restrict__ Ah, const half_t* __restrict__ Al,
               half_t* __restrict__ Nh, half_t* __restrict__ Nl,
               const half_t* __restrict__ Wh, const half_t* __restrict__ Wl,
               const float* __restrict__ bias, float gout[2][4],
               int n0w, int lrow, int kgrp)
{
    constexpr int NS = K / 32;
    const int arow = lrow * LDA;
    const size_t bc0 = (size_t)(n0w + lrow) * K;
    const size_t bc1 = (size_t)(n0w + 16 + lrow) * K;
    const float bb0 = bias[n0w + lrow];
    const float bb1 = bias[n0w + 16 + lrow];

    half8 Bh0[3], Bl0[3], Bh1[3], Bl1[3];
    #pragma unroll
    for (int p = 0; p < (NS < 2 ? NS : 2); ++p) {
        const int ko = p * 32 + kgrp * 8;
        Bh0[p] = *(const half8*)(Wh + bc0 + ko);
        Bl0[p] = *(const half8*)(Wl + bc0 + ko);
        Bh1[p] = *(const half8*)(Wh + bc1 + ko);
        Bl1[p] = *(const half8*)(Wl + bc1 + ko);
    }
    half8 Aah[2], Aal[2];
    Aah[0] = *(const half8*)&Ah[arow + kgrp * 8];
    Aal[0] = *(const half8*)&Al[arow + kgrp * 8];
    SGB(0x20, 2 + (NS < 2 ? NS : 2) * 4);  // bias + B preloads first
    SGB(0x100, 2);                         // A slot-0 reads

    f32x4 acc[2] = {};
    #pragma unroll
    for (int k = 0; k < NS; ++k) {
        if (k + 2 < NS) {                  // prefetch B for step k+2
            const int ps = (k + 2) % 3;
            const int ko = (k + 2) * 32 + kgrp * 8;
            Bh0[ps] = *(const half8*)(Wh + bc0 + ko);
            Bl0[ps] = *(const half8*)(Wl + bc0 + ko);
            Bh1[ps] = *(const half8*)(Wh + bc1 + ko);
            Bl1[ps] = *(const half8*)(Wl + bc1 + ko);
        }
        if (k + 1 < NS) {                  // prefetch A for step k+1
            const int koc = (k + 1) * 32 + kgrp * 8;
            Aah[(k + 1) & 1] = *(const half8*)&Ah[arow + koc];
            Aal[(k + 1) & 1] = *(const half8*)&Al[arow + koc];
        }
        const int cs = k % 3, ca = k & 1;
        acc[0] = MFMA16(Aah[ca], Bh0[cs], acc[0]);
        acc[1] = MFMA16(Aah[ca], Bh1[cs], acc[1]);
        acc[0] = MFMA16(Aah[ca], Bl0[cs], acc[0]);
        acc[1] = MFMA16(Aah[ca], Bl1[cs], acc[1]);
        acc[0] = MFMA16(Aal[ca], Bh0[cs], acc[0]);
        acc[1] = MFMA16(Aal[ca], Bh1[cs], acc[1]);
        if (k + 2 < NS) SGB(0x20, 4);
        if (k + 1 < NS) SGB(0x100, 2);
        SGB(0x8, 6);
    }
    // no barrier needed before epilogue: writes go to the OTHER buffer
    #pragma unroll
    for (int fn = 0; fn < 2; ++fn) {
        const int col = n0w + fn * 16 + lrow;
        const float bc = fn ? bb1 : bb0;
        #pragma unroll
        for (int r = 0; r < 4; ++r) {
            const int row = kgrp * 4 + r;
            const float pre = acc[fn][r] + bc;
            float g, h;
            if (pre > 0.f) { g = 1.f; h = pre; }
            else           { g = __expf(pre); h = g - 1.f; }
            gout[fn][r] = g;
            if constexpr (WRITE_H) {
                const half_t hh = (half_t)h;
                Nh[row * LDA + col] = hh;
                Nl[row * LDA + col] = (half_t)(h - (float)hh);
            }
        }
    }
    __syncthreads();
}

// ---------------- bwd mid step: C' = (C @ T^T) * G  (G from regs) ----------------
__device__ __forceinline__
void bwd_mid(half_t* __restrict__ Ch, half_t* __restrict__ Cl,
             const half_t* __restrict__ Th, const half_t* __restrict__ Tl,
             const float gpre[2][4], int n0w, int lrow, int kgrp)
{
    const int ar0 = (0 * 16 + lrow) * LDA;
    const int ar1 = (1 * 16 + lrow) * LDA;
    const int ar2 = (2 * 16 + lrow) * LDA;
    const size_t bc0 = (size_t)(n0w + lrow) * 256;
    const size_t bc1 = (size_t)(n0w + 16 + lrow) * 256;

    half8 Bh0[3], Bl0[3], Bh1[3], Bl1[3];
    #pragma unroll
    for (int p = 0; p < 2; ++p) {
        const int ko = p * 32 + kgrp * 8;
        Bh0[p] = *(const half8*)(Th + bc0 + ko);
        Bl0[p] = *(const half8*)(Tl + bc0 + ko);
        Bh1[p] = *(const half8*)(Th + bc1 + ko);
        Bl1[p] = *(const half8*)(Tl + bc1 + ko);
    }
    SGB(0x20, 8);                          // B preloads issue first

    f32x4 acc[3][2] = {};
    #pragma unroll
    for (int k = 0; k < 8; ++k) {
        if (k + 2 < 8) {                   // prefetch B for step k+2
            const int ps = (k + 2) % 3;
            const int ko = (k + 2) * 32 + kgrp * 8;
            Bh0[ps] = *(const half8*)(Th + bc0 + ko);
            Bl0[ps] = *(const half8*)(Tl + bc0 + ko);
            Bh1[ps] = *(const half8*)(Th + bc1 + ko);
            Bl1[ps] = *(const half8*)(Tl + bc1 + ko);
        }
        const int cs = k % 3;
        const int koc = k * 32 + kgrp * 8;
        const half8 ah0 = *(const half8*)&Ch[ar0 + koc];
        const half8 al0 = *(const half8*)&Cl[ar0 + koc];
        const half8 ah1 = *(const half8*)&Ch[ar1 + koc];
        const half8 al1 = *(const half8*)&Cl[ar1 + koc];
        const half8 ah2 = *(const half8*)&Ch[ar2 + koc];
        const half8 al2 = *(const half8*)&Cl[ar2 + koc];
        acc[0][0] = MFMA16(ah0, Bh0[cs], acc[0][0]);
        acc[1][0] = MFMA16(ah1, Bh0[cs], acc[1][0]);
        acc[2][0] = MFMA16(ah2, Bh0[cs], acc[2][0]);
        acc[0][1] = MFMA16(ah0, Bh1[cs], acc[0][1]);
        acc[1][1] = MFMA16(ah1, Bh1[cs], acc[1][1]);
        acc[2][1] = MFMA16(ah2, Bh1[cs], acc[2][1]);
        acc[0][0] = MFMA16(ah0, Bl0[cs], acc[0][0]);
        acc[1][0] = MFMA16(ah1, Bl0[cs], acc[1][0]);
        acc[2][0] = MFMA16(ah2, Bl0[cs], acc[2][0]);
        acc[0][1] = MFMA16(ah0, Bl1[cs], acc[0][1]);
        acc[1][1] = MFMA16(ah1, Bl1[cs], acc[1][1]);
        acc[2][1] = MFMA16(ah2, Bl1[cs], acc[2][1]);
        acc[0][0] = MFMA16(al0, Bh0[cs], acc[0][0]);
        acc[1][0] = MFMA16(al1, Bh0[cs], acc[1][0]);
        acc[2][0] = MFMA16(al2, Bh0[cs], acc[2][0]);
        acc[0][1] = MFMA16(al0, Bh1[cs], acc[0][1]);
        acc[1][1] = MFMA16(al1, Bh1[cs], acc[1][1]);
        acc[2][1] = MFMA16(al2, Bh1[cs], acc[2][1]);
        if (k + 2 < 8) SGB(0x20, 4);
        SGB(0x100, 6);
        SGB(0x8, 18);
    }
    __syncthreads();          // all k-loop reads of C complete
    #pragma unroll
    for (int fn = 0; fn < 2; ++fn) {
        const int col = n0w + fn * 16 + lrow;
        #pragma unroll
        for (int fm = 0; fm < 3; ++fm) {
            #pragma unroll
            for (int r = 0; r < 4; ++r) {
                const int row = fm * 16 + kgrp * 4 + r;
                const float v = acc[fm][fn][r] * gpre[fn][r];
                const half_t h = (half_t)v;
                Ch[row * LDA + col] = h;
                Cl[row * LDA + col] = (half_t)(v - (float)h);
            }
        }
    }
    __syncthreads();
}

// ---------------- fully fused forward+backward ----------------
__global__ __launch_bounds__(512, 4)
void netgrad_fused(const float* __restrict__ x,
                   const half_t* __restrict__ W1h, const half_t* __restrict__ W1l, const float* __restrict__ b1,
                   const half_t* __restrict__ W2h, const half_t* __restrict__ W2l, const float* __restrict__ b2,
                   const half_t* __restrict__ W3h, const half_t* __restrict__ W3l, const float* __restrict__ b3,
                   const half_t* __restrict__ W4h, const half_t* __restrict__ W4l, const float* __restrict__ b4,
                   const float* __restrict__ W5,
                   const half_t* __restrict__ T4h, const half_t* __restrict__ T4l,
                   const half_t* __restrict__ T3h, const half_t* __restrict__ T3l,
                   const half_t* __restrict__ T2h, const half_t* __restrict__ T2l,
                   const half_t* __restrict__ T1h, const half_t* __restrict__ T1l,
                   float* __restrict__ out)
{
    __shared__ half_t Ch[48 * LDA];
    __shared__ half_t Cl[48 * LDA];
    half_t* B0h = Ch;                  // fwd ping buffer: rows 0-15
    half_t* B0l = Cl;
    half_t* B1h = Ch + 16 * LDA;       // fwd pong buffer: rows 16-31
    half_t* B1l = Cl + 16 * LDA;
    const int tid = threadIdx.x;
    const int m0s = blockIdx.x * 16;   // sample base

    // ---- load + split x [16][64] into buf0 ----
    if (tid < 256) {
        const int row = tid >> 4, c4 = (tid & 15) * 4;
        const float4 v = *(const float4*)(x + (size_t)(m0s + row) * 64 + c4);
        const float vv[4] = {v.x, v.y, v.z, v.w};
        #pragma unroll
        for (int j = 0; j < 4; ++j) {
            const half_t h = (half_t)vv[j];
            B0h[row * LDA + c4 + j] = h;
            B0l[row * LDA + c4 + j] = (half_t)(vv[j] - (float)h);
        }
    }
    __syncthreads();

    const int lane = tid & 63, lrow = lane & 15, kgrp = lane >> 4;
    const int wave = tid >> 6;
    const int n0w = wave * 32;

    // ---- forward: G_i stay in registers (lane mapping == bwd consumer) ----
    float G1r[2][4], G2r[2][4], G3r[2][4], G4r[2][4];
    fwd_layer< 64, true >(B0h, B0l, B1h, B1l, W1h, W1l, b1, G1r, n0w, lrow, kgrp);
    fwd_layer<256, true >(B1h, B1l, B0h, B0l, W2h, W2l, b2, G2r, n0w, lrow, kgrp);
    fwd_layer<256, true >(B0h, B0l, B1h, B1l, W3h, W3l, b3, G3r, n0w, lrow, kgrp);
    // prefetch W5 values needed by expand (hide under L4 k-loop)
    float w5v[2][3];
    #pragma unroll
    for (int fn = 0; fn < 2; ++fn) {
        const int k = n0w + fn * 16 + lrow;
        #pragma unroll
        for (int o = 0; o < 3; ++o) w5v[fn][o] = W5[o * 256 + k];
    }
    fwd_layer<256, false>(B1h, B1l, nullptr, nullptr, W4h, W4l, b4, G4r, n0w, lrow, kgrp);

    // ---- expand: C0[o*16+s][k] = W5[o][k] * G4[s][k], all from regs ----
    #pragma unroll
    for (int fn = 0; fn < 2; ++fn) {
        const int k = n0w + fn * 16 + lrow;
        #pragma unroll
        for (int o = 0; o < 3; ++o)
            #pragma unroll
            for (int r = 0; r < 4; ++r) {
                const int s = kgrp * 4 + r;
                const float v = w5v[fn][o] * G4r[fn][r];
                const half_t h = (half_t)v;
                Ch[(o * 16 + s) * LDA + k] = h;
                Cl[(o * 16 + s) * LDA + k] = (half_t)(v - (float)h);
            }
    }
    __syncthreads();

    // ---- backward chain (gpre loads precede each phase's k-loop) ----
    {
        float gp[2][4];
        #pragma unroll
        for (int fn = 0; fn < 2; ++fn) {
            const int col = n0w + fn * 16 + lrow;
            #pragma unroll
            for (int r = 0; r < 4; ++r)
                gp[fn][r] = G3r[fn][r];
        }
        bwd_mid(Ch, Cl, T4h, T4l, gp, n0w, lrow, kgrp);
    }
    bwd_mid(Ch, Cl, T3h, T3l, G2r, n0w, lrow, kgrp);
    bwd_mid(Ch, Cl, T2h, T2l, G1r, n0w, lrow, kgrp);

    // ---- final: [48][256] @ T1[64][256]^T -> out rows (m0s+s)*3+o ----
    {
        const int fnf  = wave & 3;
        const int colf = fnf * 16 + lrow;
        const size_t bcf = (size_t)colf * 256;
        if (wave < 4) {
            f32x4 acc[2] = {};
            half8 Bh[3], Bl[3];
            #pragma unroll
            for (int p = 0; p < 2; ++p) {
                const int ko = p * 32 + kgrp * 8;
                Bh[p] = *(const half8*)(T1h + bcf + ko);
                Bl[p] = *(const half8*)(T1l + bcf + ko);
            }
            #pragma unroll
            for (int k = 0; k < 8; ++k) {
                if (k + 2 < 8) {
                    const int ps = (k + 2) % 3;
                    const int ko = (k + 2) * 32 + kgrp * 8;
                    Bh[ps] = *(const half8*)(T1h + bcf + ko);
                    Bl[ps] = *(const half8*)(T1l + bcf + ko);
                }
                const int cs = k % 3;
                const int koc = k * 32 + kgrp * 8;
                #pragma unroll
                for (int fm = 0; fm < 2; ++fm) {
                    const half8 ah = *(const half8*)&Ch[(fm * 16 + lrow) * LDA + koc];
                    const half8 al = *(const half8*)&Cl[(fm * 16 + lrow) * LDA + koc];
                    acc[fm] = MFMA16(ah, Bh[cs], acc[fm]);
                    acc[fm] = MFMA16(ah, Bl[cs], acc[fm]);
                    acc[fm] = MFMA16(al, Bh[cs], acc[fm]);
                }
            }
            #pragma unroll
            for (int fm = 0; fm < 2; ++fm)
                #pragma unroll
                for (int r = 0; r < 4; ++r) {
                    const int s = kgrp * 4 + r;
                    out[((size_t)(m0s + s) * 3 + fm) * 64 + colf] = acc[fm][r];
                }
        } else {
            f32x4 acc = {};
            half8 Bh[3], Bl[3];
            #pragma unroll
            for (int p = 0; p < 2; ++p) {
                const int ko = p * 32 + kgrp * 8;
                Bh[p] = *(const half8*)(T1h + bcf + ko);
                Bl[p] = *(const half8*)(T1l + bcf + ko);
            }
            #pragma unroll
            for (int k = 0; k < 8; ++k) {
                if (k + 2 < 8) {
                    const int ps = (k + 2) % 3;
                    const int ko = (k + 2) * 32 + kgrp * 8;
                    Bh[ps] = *(const half8*)(T1h + bcf + ko);
                    Bl[ps] = *(const half8*)(T1l + bcf + ko);
                }
                const int cs = k % 3;
                const int koc = k * 32 + kgrp * 8;
                const half8 ah = *(const half8*)&Ch[(2 * 16 + lrow) * LDA + koc];
                const half8 al = *(const half8*)&Cl[(2 * 16 + lrow) * LDA + koc];
                acc = MFMA16(ah, Bh[cs], acc);
                acc = MFMA16(ah, Bl[cs], acc);
                acc = MFMA16(al, Bh[cs], acc);
            }
            #pragma unroll
            for (int r = 0; r < 4; ++r) {
                const int s = kgrp * 4 + r;
                out[((size_t)(m0s + s) * 3 + 2) * 64 + colf] = acc[r];
            }
        }
    }
}

extern "C" void kernel_launch(void* const* d_in, const int* in_sizes, int n_in,
                              void* d_out, int out_size, void* d_ws, size_t ws_size,
                              hipStream_t stream)
{
    const float* x  = (const float*)d_in[0];
    const float* W1 = (const float*)d_in[1];
    const float* b1 = (const float*)d_in[2];
    const float* W2 = (const float*)d_in[3];
    const float* b2 = (const float*)d_in[4];
    const float* W3 = (const float*)d_in[5];
    const float* b3 = (const float*)d_in[6];
    const float* W4 = (const float*)d_in[7];
    const float* b4 = (const float*)d_in[8];
    const float* W5 = (const float*)d_in[9];

    // ---- workspace carve (~2.6 MB: weight splits only) ----
    char* p = (char*)d_ws;
    half_t* W1h = (half_t*)p; p += 256 * 64 * 2;
    half_t* W1l = (half_t*)p; p += 256 * 64 * 2;
    half_t* T1h = (half_t*)p; p += 64 * 256 * 2;
    half_t* T1l = (half_t*)p; p += 64 * 256 * 2;
    half_t* W2h = (half_t*)p; p += 256 * 256 * 2;
    half_t* W2l = (half_t*)p; p += 256 * 256 * 2;
    half_t* T2h = (half_t*)p; p += 256 * 256 * 2;
    half_t* T2l = (half_t*)p; p += 256 * 256 * 2;
    half_t* W3h = (half_t*)p; p += 256 * 256 * 2;
    half_t* W3l = (half_t*)p; p += 256 * 256 * 2;
    half_t* T3h = (half_t*)p; p += 256 * 256 * 2;
    half_t* T3l = (half_t*)p; p += 256 * 256 * 2;
    half_t* W4h = (half_t*)p; p += 256 * 256 * 2;
    half_t* W4l = (half_t*)p; p += 256 * 256 * 2;
    half_t* T4h = (half_t*)p; p += 256 * 256 * 2;
    half_t* T4l = (half_t*)p; p += 256 * 256 * 2;

    prep_split<<<208, 256, 0, stream>>>(W1, W2, W3, W4,
        W1h, W1l, T1h, T1l, W2h, W2l, T2h, T2l,
        W3h, W3l, T3h, T3l, W4h, W4l, T4h, T4l);

    netgrad_fused<<<Bsz / 16, 512, 0, stream>>>(x,
        W1h, W1l, b1,  W2h, W2l, b2,  W3h, W3l, b3,  W4h, W4l, b4,
        W5,  T4h, T4l, T3h, T3l, T2h, T2l, T1h, T1l,
        (float*)d_out);
}

// Round 8
// 63.891 us; speedup vs baseline: 1.8164x; 1.8164x over previous
//
#include <hip/hip_runtime.h>
#include <cstdint>
#include <cstddef>

// NetGrad J = W5 D4 W4 D3 W3 D2 W2 D1 W1, output [B,3,64].
// Single fused kernel per 16-sample block: fwd chain (H in LDS, G1..G4 in
// registers, same lane mapping as bwd consumer) then bwd chain (48-row C in
// LDS, row layout o*16+s). 2-TERM split MFMA: A exact (hi+lo f16), B = f16
// hi only -> (Ah+Al)*Bh. Halves global B-traffic, cuts MFMA 33% vs 3-term.
// 512 threads = 8 waves, each owning a 32-col span (fn=2 fragments).

typedef _Float16 half_t;
typedef __attribute__((ext_vector_type(8))) _Float16 half8;
typedef __attribute__((ext_vector_type(4))) float f32x4;

#define MFMA16(a, b, c) __builtin_amdgcn_mfma_f32_16x16x32_f16(a, b, c, 0, 0, 0)

constexpr int Bsz = 8192;
constexpr int D   = 256;
constexpr int LDA = 264;          // LDS row stride in halves (528 B)

// ---------------- prep: f16-hi split, native + transposed, all weights ----------------
__global__ __launch_bounds__(256)
void prep_split(const float* __restrict__ W1, const float* __restrict__ W2,
                const float* __restrict__ W3, const float* __restrict__ W4,
                half_t* W1h, half_t* T1h, half_t* W2h, half_t* T2h,
                half_t* W3h, half_t* T3h, half_t* W4h, half_t* T4h)
{
    __shared__ float tile[32][33];
    const int bid = blockIdx.x;
    const float* src; half_t *sh, *th; int C, bx, by;
    if (bid < 16) {
        src = W1; sh = W1h; th = T1h;
        C = 64; bx = bid & 1; by = bid >> 1;
    } else {
        const int q = bid - 16, j = q >> 6, lo = q & 63;
        bx = lo & 7; by = lo >> 3; C = 256;
        if (j == 0)      { src = W2; sh = W2h; th = T2h; }
        else if (j == 1) { src = W3; sh = W3h; th = T3h; }
        else             { src = W4; sh = W4h; th = T4h; }
    }
    const int R = 256;
    const int tx = threadIdx.x & 31, ty = threadIdx.x >> 5;
    #pragma unroll
    for (int i = 0; i < 32; i += 8) {
        const size_t o = (size_t)(by * 32 + ty + i) * C + bx * 32 + tx;
        const float v = src[o];
        tile[ty + i][tx] = v;
        sh[o] = (half_t)v;
    }
    __syncthreads();
    #pragma unroll
    for (int i = 0; i < 32; i += 8) {
        const float v = tile[tx][ty + i];
        const size_t o = (size_t)(bx * 32 + ty + i) * R + by * 32 + tx;
        th[o] = (half_t)v;
    }
}

// ---------------- fwd layer: pre = A @ W^T + b; G -> regs; H' = elu -> LDS ----------------
__device__ __forceinline__
void fwd_layer(half_t* __restrict__ Ah, half_t* __restrict__ Al,
               const half_t* __restrict__ Wh,
               const float* __restrict__ bias, float gout[2][4],
               int K, bool writeH, int n0w, int lrow, int kgrp)
{
    f32x4 acc[2] = {};
    for (int k0 = 0; k0 < K; k0 += 32) {
        const int ko = k0 + kgrp * 8;
        const half8 ah = *(const half8*)&Ah[lrow * LDA + ko];
        const half8 al = *(const half8*)&Al[lrow * LDA + ko];
        #pragma unroll
        for (int fn = 0; fn < 2; ++fn) {
            const int col = n0w + fn * 16 + lrow;
            const half8 bh = *(const half8*)(Wh + (size_t)col * K + ko);
            acc[fn] = MFMA16(ah, bh, acc[fn]);
            acc[fn] = MFMA16(al, bh, acc[fn]);
        }
    }
    __syncthreads();                      // all reads of A done before overwrite
    #pragma unroll
    for (int fn = 0; fn < 2; ++fn) {
        const int col = n0w + fn * 16 + lrow;
        const float bc = bias[col];
        #pragma unroll
        for (int r = 0; r < 4; ++r) {
            const int row = kgrp * 4 + r;
            const float pre = acc[fn][r] + bc;
            float g, h;
            if (pre > 0.f) { g = 1.f; h = pre; }
            else           { g = __expf(pre); h = g - 1.f; }
            gout[fn][r] = g;
            if (writeH) {
                const half_t hh = (half_t)h;
                Ah[row * LDA + col] = hh;
                Al[row * LDA + col] = (half_t)(h - (float)hh);
            }
        }
    }
    __syncthreads();
}

// ---------------- bwd mid step: C' = (C @ T^T) * G  (G from regs) ----------------
__device__ __forceinline__
void bwd_mid(half_t* __restrict__ Ch, half_t* __restrict__ Cl,
             const half_t* __restrict__ Th,
             const float gpre[2][4], int n0w, int lrow, int kgrp)
{
    f32x4 acc[3][2] = {};
    for (int k0 = 0; k0 < 256; k0 += 32) {
        const int ko = k0 + kgrp * 8;
        half8 ah[3], al[3];
        #pragma unroll
        for (int fm = 0; fm < 3; ++fm) {
            ah[fm] = *(const half8*)&Ch[(fm * 16 + lrow) * LDA + ko];
            al[fm] = *(const half8*)&Cl[(fm * 16 + lrow) * LDA + ko];
        }
        #pragma unroll
        for (int fn = 0; fn < 2; ++fn) {
            const int col = n0w + fn * 16 + lrow;
            const half8 bh = *(const half8*)(Th + (size_t)col * 256 + ko);
            #pragma unroll
            for (int fm = 0; fm < 3; ++fm) {
                acc[fm][fn] = MFMA16(ah[fm], bh, acc[fm][fn]);
                acc[fm][fn] = MFMA16(al[fm], bh, acc[fm][fn]);
            }
        }
    }
    __syncthreads();          // all k-loop reads of C complete
    #pragma unroll
    for (int fn = 0; fn < 2; ++fn) {
        const int col = n0w + fn * 16 + lrow;
        #pragma unroll
        for (int fm = 0; fm < 3; ++fm) {
            #pragma unroll
            for (int r = 0; r < 4; ++r) {
                const int row = fm * 16 + kgrp * 4 + r;
                const float v = acc[fm][fn][r] * gpre[fn][r];
                const half_t h = (half_t)v;
                Ch[row * LDA + col] = h;
                Cl[row * LDA + col] = (half_t)(v - (float)h);
            }
        }
    }
    __syncthreads();
}

// ---------------- fully fused forward+backward ----------------
__global__ __launch_bounds__(512, 4)
void netgrad_fused(const float* __restrict__ x,
                   const half_t* __restrict__ W1h, const float* __restrict__ b1,
                   const half_t* __restrict__ W2h, const float* __restrict__ b2,
                   const half_t* __restrict__ W3h, const float* __restrict__ b3,
                   const half_t* __restrict__ W4h, const float* __restrict__ b4,
                   const float* __restrict__ W5,
                   const half_t* __restrict__ T4h, const half_t* __restrict__ T3h,
                   const half_t* __restrict__ T2h, const half_t* __restrict__ T1h,
                   float* __restrict__ out)
{
    __shared__ half_t Ch[48 * LDA];
    __shared__ half_t Cl[48 * LDA];
    half_t* Ahs = Ch;                      // fwd H chain aliases C rows 0..15
    half_t* Als = Cl;
    const int tid = threadIdx.x;
    const int m0s = blockIdx.x * 16;       // sample base

    // ---- load + split x [16][64] ----
    if (tid < 256) {
        const int row = tid >> 4, c4 = (tid & 15) * 4;
        const float4 v = *(const float4*)(x + (size_t)(m0s + row) * 64 + c4);
        const float vv[4] = {v.x, v.y, v.z, v.w};
        #pragma unroll
        for (int j = 0; j < 4; ++j) {
            const half_t h = (half_t)vv[j];
            Ahs[row * LDA + c4 + j] = h;
            Als[row * LDA + c4 + j] = (half_t)(vv[j] - (float)h);
        }
    }
    __syncthreads();

    const int lane = tid & 63, lrow = lane & 15, kgrp = lane >> 4;
    const int wave = tid >> 6;
    const int n0w = wave * 32;

    // ---- forward: G_i stay in registers (lane mapping == bwd consumer) ----
    float G1r[2][4], G2r[2][4], G3r[2][4], G4r[2][4];
    fwd_layer(Ahs, Als, W1h, b1, G1r,  64, true,  n0w, lrow, kgrp);
    fwd_layer(Ahs, Als, W2h, b2, G2r, 256, true,  n0w, lrow, kgrp);
    fwd_layer(Ahs, Als, W3h, b3, G3r, 256, true,  n0w, lrow, kgrp);
    fwd_layer(Ahs, Als, W4h, b4, G4r, 256, false, n0w, lrow, kgrp);

    // ---- expand: C0[o*16+s][k] = W5[o][k] * G4[s][k], G4 from regs ----
    #pragma unroll
    for (int fn = 0; fn < 2; ++fn) {
        const int k = n0w + fn * 16 + lrow;
        float w5v[3];
        #pragma unroll
        for (int o = 0; o < 3; ++o) w5v[o] = W5[o * 256 + k];
        #pragma unroll
        for (int o = 0; o < 3; ++o)
            #pragma unroll
            for (int r = 0; r < 4; ++r) {
                const int s = kgrp * 4 + r;
                const float v = w5v[o] * G4r[fn][r];
                const half_t h = (half_t)v;
                Ch[(o * 16 + s) * LDA + k] = h;
                Cl[(o * 16 + s) * LDA + k] = (half_t)(v - (float)h);
            }
    }
    __syncthreads();

    // ---- backward chain ----
    bwd_mid(Ch, Cl, T4h, G3r, n0w, lrow, kgrp);
    bwd_mid(Ch, Cl, T3h, G2r, n0w, lrow, kgrp);
    bwd_mid(Ch, Cl, T2h, G1r, n0w, lrow, kgrp);

    // ---- final: [48][256] @ T1[64][256]^T -> out rows (m0s+s)*3+o ----
    {
        const int fnf  = wave & 3;
        const int colf = fnf * 16 + lrow;
        const size_t bcf = (size_t)colf * 256;
        if (wave < 4) {
            f32x4 acc[2] = {};
            for (int k0 = 0; k0 < 256; k0 += 32) {
                const int ko = k0 + kgrp * 8;
                const half8 bh = *(const half8*)(T1h + bcf + ko);
                #pragma unroll
                for (int fm = 0; fm < 2; ++fm) {
                    const half8 ah = *(const half8*)&Ch[(fm * 16 + lrow) * LDA + ko];
                    const half8 al = *(const half8*)&Cl[(fm * 16 + lrow) * LDA + ko];
                    acc[fm] = MFMA16(ah, bh, acc[fm]);
                    acc[fm] = MFMA16(al, bh, acc[fm]);
                }
            }
            #pragma unroll
            for (int fm = 0; fm < 2; ++fm)
                #pragma unroll
                for (int r = 0; r < 4; ++r) {
                    const int s = kgrp * 4 + r;
                    out[((size_t)(m0s + s) * 3 + fm) * 64 + colf] = acc[fm][r];
                }
        } else {
            f32x4 acc = {};
            for (int k0 = 0; k0 < 256; k0 += 32) {
                const int ko = k0 + kgrp * 8;
                const half8 bh = *(const half8*)(T1h + bcf + ko);
                const half8 ah = *(const half8*)&Ch[(2 * 16 + lrow) * LDA + ko];
                const half8 al = *(const half8*)&Cl[(2 * 16 + lrow) * LDA + ko];
                acc = MFMA16(ah, bh, acc);
                acc = MFMA16(al, bh, acc);
            }
            #pragma unroll
            for (int r = 0; r < 4; ++r) {
                const int s = kgrp * 4 + r;
                out[((size_t)(m0s + s) * 3 + 2) * 64 + colf] = acc[r];
            }
        }
    }
}

extern "C" void kernel_launch(void* const* d_in, const int* in_sizes, int n_in,
                              void* d_out, int out_size, void* d_ws, size_t ws_size,
                              hipStream_t stream)
{
    const float* x  = (const float*)d_in[0];
    const float* W1 = (const float*)d_in[1];
    const float* b1 = (const float*)d_in[2];
    const float* W2 = (const float*)d_in[3];
    const float* b2 = (const float*)d_in[4];
    const float* W3 = (const float*)d_in[5];
    const float* b3 = (const float*)d_in[6];
    const float* W4 = (const float*)d_in[7];
    const float* b4 = (const float*)d_in[8];
    const float* W5 = (const float*)d_in[9];

    // ---- workspace carve (~1.3 MB: f16-hi weight tables only) ----
    char* p = (char*)d_ws;
    half_t* W1h = (half_t*)p; p += 256 * 64 * 2;
    half_t* T1h = (half_t*)p; p += 64 * 256 * 2;
    half_t* W2h = (half_t*)p; p += 256 * 256 * 2;
    half_t* T2h = (half_t*)p; p += 256 * 256 * 2;
    half_t* W3h = (half_t*)p; p += 256 * 256 * 2;
    half_t* T3h = (half_t*)p; p += 256 * 256 * 2;
    half_t* W4h = (half_t*)p; p += 256 * 256 * 2;
    half_t* T4h = (half_t*)p; p += 256 * 256 * 2;

    prep_split<<<208, 256, 0, stream>>>(W1, W2, W3, W4,
        W1h, T1h, W2h, T2h, W3h, T3h, W4h, T4h);

    netgrad_fused<<<Bsz / 16, 512, 0, stream>>>(x,
        W1h, b1,  W2h, b2,  W3h, b3,  W4h, b4,
        W5,  T4h, T3h, T2h, T1h,
        (float*)d_out);
}

// Round 9
// 62.796 us; speedup vs baseline: 1.8481x; 1.0174x over previous
//
#include <hip/hip_runtime.h>
#include <cstdint>
#include <cstddef>

// NetGrad J = W5 D4 W4 D3 W3 D2 W2 D1 W1, output [B,3,64].
// Fused per-16-sample block. fwd: single-term f16 MFMA (H hi-only), ping-pong
// H buffers, 1 barrier/layer, G1..G4 in registers. bwd: 48-row C (o*16+s) in
// LDS hi/lo, 2-term MFMA (Chi+Clo)*Bhi, B-fragments burst-hoisted 2 k-steps
// ahead (static array, fully unrolled), setprio around MFMA clusters.

typedef _Float16 half_t;
typedef __attribute__((ext_vector_type(8))) _Float16 half8;
typedef __attribute__((ext_vector_type(4))) float f32x4;

#define MFMA16(a, b, c) __builtin_amdgcn_mfma_f32_16x16x32_f16(a, b, c, 0, 0, 0)

constexpr int Bsz = 8192;
constexpr int D   = 256;
constexpr int LDA = 264;          // LDS row stride in halves (528 B)

// ---------------- prep: f16-hi tables, native + transposed ----------------
__global__ __launch_bounds__(256)
void prep_split(const float* __restrict__ W1, const float* __restrict__ W2,
                const float* __restrict__ W3, const float* __restrict__ W4,
                half_t* W1h, half_t* T1h, half_t* W2h, half_t* T2h,
                half_t* W3h, half_t* T3h, half_t* W4h, half_t* T4h)
{
    __shared__ float tile[32][33];
    const int bid = blockIdx.x;
    const float* src; half_t *sh, *th; int C, bx, by;
    if (bid < 16) {
        src = W1; sh = W1h; th = T1h;
        C = 64; bx = bid & 1; by = bid >> 1;
    } else {
        const int q = bid - 16, j = q >> 6, lo = q & 63;
        bx = lo & 7; by = lo >> 3; C = 256;
        if (j == 0)      { src = W2; sh = W2h; th = T2h; }
        else if (j == 1) { src = W3; sh = W3h; th = T3h; }
        else             { src = W4; sh = W4h; th = T4h; }
    }
    const int R = 256;
    const int tx = threadIdx.x & 31, ty = threadIdx.x >> 5;
    #pragma unroll
    for (int i = 0; i < 32; i += 8) {
        const size_t o = (size_t)(by * 32 + ty + i) * C + bx * 32 + tx;
        const float v = src[o];
        tile[ty + i][tx] = v;
        sh[o] = (half_t)v;
    }
    __syncthreads();
    #pragma unroll
    for (int i = 0; i < 32; i += 8) {
        const float v = tile[tx][ty + i];
        const size_t o = (size_t)(bx * 32 + ty + i) * R + by * 32 + tx;
        th[o] = (half_t)v;
    }
}

// ---------------- fwd layer: pre = A @ W^T + b; G -> regs; H' -> other buffer ----------------
template<int K, bool WRITE_H>
__device__ __forceinline__
void fwd_layer(const half_t* __restrict__ Acur, half_t* __restrict__ Anxt,
               const half_t* __restrict__ Wh,
               const float* __restrict__ bias, float gout[2][4],
               int n0w, int lrow, int kgrp)
{
    const int arow = lrow * LDA;
    const size_t bc0 = (size_t)(n0w + lrow) * K;
    const size_t bc1 = (size_t)(n0w + 16 + lrow) * K;

    f32x4 acc[2] = {};
    #pragma unroll
    for (int h = 0; h < K / 64; ++h) {
        half8 B[4];                             // 2 cols x 2 k-steps, burst
        B[0] = *(const half8*)(Wh + bc0 + h * 64 + kgrp * 8);
        B[1] = *(const half8*)(Wh + bc1 + h * 64 + kgrp * 8);
        B[2] = *(const half8*)(Wh + bc0 + h * 64 + 32 + kgrp * 8);
        B[3] = *(const half8*)(Wh + bc1 + h * 64 + 32 + kgrp * 8);
        #pragma unroll
        for (int p = 0; p < 2; ++p) {
            const int ko = h * 64 + p * 32 + kgrp * 8;
            const half8 ah = *(const half8*)&Acur[arow + ko];
            acc[0] = MFMA16(ah, B[2 * p + 0], acc[0]);
            acc[1] = MFMA16(ah, B[2 * p + 1], acc[1]);
        }
    }
    #pragma unroll
    for (int fn = 0; fn < 2; ++fn) {
        const int col = n0w + fn * 16 + lrow;
        const float bc = bias[col];
        #pragma unroll
        for (int r = 0; r < 4; ++r) {
            const int row = kgrp * 4 + r;
            const float pre = acc[fn][r] + bc;
            float g, h;
            if (pre > 0.f) { g = 1.f; h = pre; }
            else           { g = __expf(pre); h = g - 1.f; }
            gout[fn][r] = g;
            if constexpr (WRITE_H)
                Anxt[row * LDA + col] = (half_t)h;
        }
    }
    __syncthreads();
}

// ---------------- bwd mid step: C' = (C @ T^T) * G  (G from regs) ----------------
__device__ __forceinline__
void bwd_mid(half_t* __restrict__ Ch, half_t* __restrict__ Cl,
             const half_t* __restrict__ Th,
             const float gpre[2][4], int n0w, int lrow, int kgrp)
{
    const int ar0 = (0 * 16 + lrow) * LDA;
    const int ar1 = (1 * 16 + lrow) * LDA;
    const int ar2 = (2 * 16 + lrow) * LDA;
    const size_t bc0 = (size_t)(n0w + lrow) * 256;
    const size_t bc1 = (size_t)(n0w + 16 + lrow) * 256;

    f32x4 acc[3][2] = {};
    #pragma unroll
    for (int h = 0; h < 4; ++h) {
        half8 B[4];                             // 2 cols x 2 k-steps, burst
        B[0] = *(const half8*)(Th + bc0 + h * 64 + kgrp * 8);
        B[1] = *(const half8*)(Th + bc1 + h * 64 + kgrp * 8);
        B[2] = *(const half8*)(Th + bc0 + h * 64 + 32 + kgrp * 8);
        B[3] = *(const half8*)(Th + bc1 + h * 64 + 32 + kgrp * 8);
        #pragma unroll
        for (int p = 0; p < 2; ++p) {
            const int ko = h * 64 + p * 32 + kgrp * 8;
            const half8 ah0 = *(const half8*)&Ch[ar0 + ko];
            const half8 al0 = *(const half8*)&Cl[ar0 + ko];
            const half8 ah1 = *(const half8*)&Ch[ar1 + ko];
            const half8 al1 = *(const half8*)&Cl[ar1 + ko];
            const half8 ah2 = *(const half8*)&Ch[ar2 + ko];
            const half8 al2 = *(const half8*)&Cl[ar2 + ko];
            const half8 b0 = B[2 * p + 0], b1 = B[2 * p + 1];
            __builtin_amdgcn_s_setprio(1);
            acc[0][0] = MFMA16(ah0, b0, acc[0][0]);
            acc[1][0] = MFMA16(ah1, b0, acc[1][0]);
            acc[2][0] = MFMA16(ah2, b0, acc[2][0]);
            acc[0][1] = MFMA16(ah0, b1, acc[0][1]);
            acc[1][1] = MFMA16(ah1, b1, acc[1][1]);
            acc[2][1] = MFMA16(ah2, b1, acc[2][1]);
            acc[0][0] = MFMA16(al0, b0, acc[0][0]);
            acc[1][0] = MFMA16(al1, b0, acc[1][0]);
            acc[2][0] = MFMA16(al2, b0, acc[2][0]);
            acc[0][1] = MFMA16(al0, b1, acc[0][1]);
            acc[1][1] = MFMA16(al1, b1, acc[1][1]);
            acc[2][1] = MFMA16(al2, b1, acc[2][1]);
            __builtin_amdgcn_s_setprio(0);
        }
    }
    __syncthreads();          // all k-loop reads of C complete
    #pragma unroll
    for (int fn = 0; fn < 2; ++fn) {
        const int col = n0w + fn * 16 + lrow;
        #pragma unroll
        for (int fm = 0; fm < 3; ++fm) {
            #pragma unroll
            for (int r = 0; r < 4; ++r) {
                const int row = fm * 16 + kgrp * 4 + r;
                const float v = acc[fm][fn][r] * gpre[fn][r];
                const half_t h = (half_t)v;
                Ch[row * LDA + col] = h;
                Cl[row * LDA + col] = (half_t)(v - (float)h);
            }
        }
    }
    __syncthreads();
}

// ---------------- fully fused forward+backward ----------------
__global__ __launch_bounds__(512, 4)
void netgrad_fused(const float* __restrict__ x,
                   const half_t* __restrict__ W1h, const float* __restrict__ b1,
                   const half_t* __restrict__ W2h, const float* __restrict__ b2,
                   const half_t* __restrict__ W3h, const float* __restrict__ b3,
                   const half_t* __restrict__ W4h, const float* __restrict__ b4,
                   const float* __restrict__ W5,
                   const half_t* __restrict__ T4h, const half_t* __restrict__ T3h,
                   const half_t* __restrict__ T2h, const half_t* __restrict__ T1h,
                   float* __restrict__ out)
{
    __shared__ half_t Ch[48 * LDA];
    __shared__ half_t Cl[48 * LDA];
    half_t* Hb0 = Ch;                      // fwd ping buffer: rows 0-15
    half_t* Hb1 = Ch + 16 * LDA;           // fwd pong buffer: rows 16-31
    const int tid = threadIdx.x;
    const int m0s = blockIdx.x * 16;       // sample base

    // ---- load x [16][64] (hi only) into buf0 ----
    if (tid < 256) {
        const int row = tid >> 4, c4 = (tid & 15) * 4;
        const float4 v = *(const float4*)(x + (size_t)(m0s + row) * 64 + c4);
        Hb0[row * LDA + c4 + 0] = (half_t)v.x;
        Hb0[row * LDA + c4 + 1] = (half_t)v.y;
        Hb0[row * LDA + c4 + 2] = (half_t)v.z;
        Hb0[row * LDA + c4 + 3] = (half_t)v.w;
    }
    __syncthreads();

    const int lane = tid & 63, lrow = lane & 15, kgrp = lane >> 4;
    const int wave = tid >> 6;
    const int n0w = wave * 32;

    // ---- forward: G_i stay in registers (lane mapping == bwd consumer) ----
    float G1r[2][4], G2r[2][4], G3r[2][4], G4r[2][4];
    fwd_layer< 64, true >(Hb0, Hb1, W1h, b1, G1r, n0w, lrow, kgrp);
    fwd_layer<256, true >(Hb1, Hb0, W2h, b2, G2r, n0w, lrow, kgrp);
    fwd_layer<256, true >(Hb0, Hb1, W3h, b3, G3r, n0w, lrow, kgrp);
    fwd_layer<256, false>(Hb1, nullptr, W4h, b4, G4r, n0w, lrow, kgrp);

    // ---- expand: C0[o*16+s][k] = W5[o][k] * G4[s][k], G4 from regs ----
    #pragma unroll
    for (int fn = 0; fn < 2; ++fn) {
        const int k = n0w + fn * 16 + lrow;
        float w5v[3];
        #pragma unroll
        for (int o = 0; o < 3; ++o) w5v[o] = W5[o * 256 + k];
        #pragma unroll
        for (int o = 0; o < 3; ++o)
            #pragma unroll
            for (int r = 0; r < 4; ++r) {
                const int s = kgrp * 4 + r;
                const float v = w5v[o] * G4r[fn][r];
                const half_t h = (half_t)v;
                Ch[(o * 16 + s) * LDA + k] = h;
                Cl[(o * 16 + s) * LDA + k] = (half_t)(v - (float)h);
            }
    }
    __syncthreads();

    // ---- backward chain ----
    bwd_mid(Ch, Cl, T4h, G3r, n0w, lrow, kgrp);
    bwd_mid(Ch, Cl, T3h, G2r, n0w, lrow, kgrp);
    bwd_mid(Ch, Cl, T2h, G1r, n0w, lrow, kgrp);

    // ---- final: [48][256] @ T1[64][256]^T -> out rows (m0s+s)*3+o ----
    {
        const int fnf  = wave & 3;
        const int colf = fnf * 16 + lrow;
        const size_t bcf = (size_t)colf * 256;
        if (wave < 4) {
            f32x4 acc[2] = {};
            #pragma unroll
            for (int h = 0; h < 4; ++h) {
                half8 B[2];
                B[0] = *(const half8*)(T1h + bcf + h * 64 + kgrp * 8);
                B[1] = *(const half8*)(T1h + bcf + h * 64 + 32 + kgrp * 8);
                #pragma unroll
                for (int p = 0; p < 2; ++p) {
                    const int ko = h * 64 + p * 32 + kgrp * 8;
                    #pragma unroll
                    for (int fm = 0; fm < 2; ++fm) {
                        const half8 ah = *(const half8*)&Ch[(fm * 16 + lrow) * LDA + ko];
                        const half8 al = *(const half8*)&Cl[(fm * 16 + lrow) * LDA + ko];
                        acc[fm] = MFMA16(ah, B[p], acc[fm]);
                        acc[fm] = MFMA16(al, B[p], acc[fm]);
                    }
                }
            }
            #pragma unroll
            for (int fm = 0; fm < 2; ++fm)
                #pragma unroll
                for (int r = 0; r < 4; ++r) {
                    const int s = kgrp * 4 + r;
                    out[((size_t)(m0s + s) * 3 + fm) * 64 + colf] = acc[fm][r];
                }
        } else {
            f32x4 acc = {};
            #pragma unroll
            for (int h = 0; h < 4; ++h) {
                half8 B[2];
                B[0] = *(const half8*)(T1h + bcf + h * 64 + kgrp * 8);
                B[1] = *(const half8*)(T1h + bcf + h * 64 + 32 + kgrp * 8);
                #pragma unroll
                for (int p = 0; p < 2; ++p) {
                    const int ko = h * 64 + p * 32 + kgrp * 8;
                    const half8 ah = *(const half8*)&Ch[(2 * 16 + lrow) * LDA + ko];
                    const half8 al = *(const half8*)&Cl[(2 * 16 + lrow) * LDA + ko];
                    acc = MFMA16(ah, B[p], acc);
                    acc = MFMA16(al, B[p], acc);
                }
            }
            #pragma unroll
            for (int r = 0; r < 4; ++r) {
                const int s = kgrp * 4 + r;
                out[((size_t)(m0s + s) * 3 + 2) * 64 + colf] = acc[r];
            }
        }
    }
}

extern "C" void kernel_launch(void* const* d_in, const int* in_sizes, int n_in,
                              void* d_out, int out_size, void* d_ws, size_t ws_size,
                              hipStream_t stream)
{
    const float* x  = (const float*)d_in[0];
    const float* W1 = (const float*)d_in[1];
    const float* b1 = (const float*)d_in[2];
    const float* W2 = (const float*)d_in[3];
    const float* b2 = (const float*)d_in[4];
    const float* W3 = (const float*)d_in[5];
    const float* b3 = (const float*)d_in[6];
    const float* W4 = (const float*)d_in[7];
    const float* b4 = (const float*)d_in[8];
    const float* W5 = (const float*)d_in[9];

    // ---- workspace carve (~1.3 MB: f16-hi weight tables only) ----
    char* p = (char*)d_ws;
    half_t* W1h = (half_t*)p; p += 256 * 64 * 2;
    half_t* T1h = (half_t*)p; p += 64 * 256 * 2;
    half_t* W2h = (half_t*)p; p += 256 * 256 * 2;
    half_t* T2h = (half_t*)p; p += 256 * 256 * 2;
    half_t* W3h = (half_t*)p; p += 256 * 256 * 2;
    half_t* T3h = (half_t*)p; p += 256 * 256 * 2;
    half_t* W4h = (half_t*)p; p += 256 * 256 * 2;
    half_t* T4h = (half_t*)p; p += 256 * 256 * 2;

    prep_split<<<208, 256, 0, stream>>>(W1, W2, W3, W4,
        W1h, T1h, W2h, T2h, W3h, T3h, W4h, T4h);

    netgrad_fused<<<Bsz / 16, 512, 0, stream>>>(x,
        W1h, b1,  W2h, b2,  W3h, b3,  W4h, b4,
        W5,  T4h, T3h, T2h, T1h,
        (float*)d_out);
}

// Round 10
// 61.430 us; speedup vs baseline: 1.8892x; 1.0222x over previous
//
#include <hip/hip_runtime.h>
#include <cstdint>
#include <cstddef>

// NetGrad J = W5 D4 W4 D3 W3 D2 W2 D1 W1, output [B,3,64].
// Fused per-16-sample block, ALL f16-hi arithmetic (weights AND chain state):
// fwd (H ping-pong, G1..G4 in regs) -> expand -> 3 bwd steps -> final.
// Two 48-row LDS arenas ping-pong every phase => exactly 1 barrier/phase (8
// total). 1-term MFMA everywhere. B-fragments burst-loaded (4 k-steps).

typedef _Float16 half_t;
typedef __attribute__((ext_vector_type(8))) _Float16 half8;
typedef __attribute__((ext_vector_type(4))) float f32x4;

#define MFMA16(a, b, c) __builtin_amdgcn_mfma_f32_16x16x32_f16(a, b, c, 0, 0, 0)

constexpr int Bsz = 8192;
constexpr int D   = 256;
constexpr int LDA = 264;          // LDS row stride in halves (528 B)

// ---------------- prep: f16-hi tables, native + transposed ----------------
__global__ __launch_bounds__(256)
void prep_split(const float* __restrict__ W1, const float* __restrict__ W2,
                const float* __restrict__ W3, const float* __restrict__ W4,
                half_t* W1h, half_t* T1h, half_t* W2h, half_t* T2h,
                half_t* W3h, half_t* T3h, half_t* W4h, half_t* T4h)
{
    __shared__ float tile[32][33];
    const int bid = blockIdx.x;
    const float* src; half_t *sh, *th; int C, bx, by;
    if (bid < 16) {
        src = W1; sh = W1h; th = T1h;
        C = 64; bx = bid & 1; by = bid >> 1;
    } else {
        const int q = bid - 16, j = q >> 6, lo = q & 63;
        bx = lo & 7; by = lo >> 3; C = 256;
        if (j == 0)      { src = W2; sh = W2h; th = T2h; }
        else if (j == 1) { src = W3; sh = W3h; th = T3h; }
        else             { src = W4; sh = W4h; th = T4h; }
    }
    const int R = 256;
    const int tx = threadIdx.x & 31, ty = threadIdx.x >> 5;
    #pragma unroll
    for (int i = 0; i < 32; i += 8) {
        const size_t o = (size_t)(by * 32 + ty + i) * C + bx * 32 + tx;
        const float v = src[o];
        tile[ty + i][tx] = v;
        sh[o] = (half_t)v;
    }
    __syncthreads();
    #pragma unroll
    for (int i = 0; i < 32; i += 8) {
        const float v = tile[tx][ty + i];
        const size_t o = (size_t)(bx * 32 + ty + i) * R + by * 32 + tx;
        th[o] = (half_t)v;
    }
}

// ---------------- fwd layer: pre = A @ W^T + b; G -> regs; H' -> Anxt ----------------
template<int K, bool WRITE_H>
__device__ __forceinline__
void fwd_layer(const half_t* __restrict__ Acur, half_t* __restrict__ Anxt,
               const half_t* __restrict__ Wh,
               const float* __restrict__ bias, float gout[2][4],
               int n0w, int lrow, int kgrp)
{
    constexpr int NS = K / 32;                 // 2 or 8
    constexpr int BURST = (NS >= 4) ? 4 : NS;  // k-steps per load burst
    const int arow = lrow * LDA;
    const size_t bc0 = (size_t)(n0w + lrow) * K;
    const size_t bc1 = (size_t)(n0w + 16 + lrow) * K;

    f32x4 acc[2] = {};
    #pragma unroll
    for (int hb = 0; hb < NS / BURST; ++hb) {
        half8 B[2 * BURST];
        #pragma unroll
        for (int p = 0; p < BURST; ++p) {
            const int ko = (hb * BURST + p) * 32 + kgrp * 8;
            B[2 * p + 0] = *(const half8*)(Wh + bc0 + ko);
            B[2 * p + 1] = *(const half8*)(Wh + bc1 + ko);
        }
        #pragma unroll
        for (int p = 0; p < BURST; ++p) {
            const int ko = (hb * BURST + p) * 32 + kgrp * 8;
            const half8 ah = *(const half8*)&Acur[arow + ko];
            acc[0] = MFMA16(ah, B[2 * p + 0], acc[0]);
            acc[1] = MFMA16(ah, B[2 * p + 1], acc[1]);
        }
    }
    #pragma unroll
    for (int fn = 0; fn < 2; ++fn) {
        const int col = n0w + fn * 16 + lrow;
        const float bc = bias[col];
        #pragma unroll
        for (int r = 0; r < 4; ++r) {
            const int row = kgrp * 4 + r;
            const float pre = acc[fn][r] + bc;
            float g, h;
            if (pre > 0.f) { g = 1.f; h = pre; }
            else           { g = __expf(pre); h = g - 1.f; }
            gout[fn][r] = g;
            if constexpr (WRITE_H)
                Anxt[row * LDA + col] = (half_t)h;
        }
    }
    __syncthreads();
}

// ---------------- bwd mid step: Cwr = (Crd @ T^T) * G  (1-term, G from regs) ----------------
__device__ __forceinline__
void bwd_mid(const half_t* __restrict__ Crd, half_t* __restrict__ Cwr,
             const half_t* __restrict__ Th,
             const float gpre[2][4], int n0w, int lrow, int kgrp)
{
    const int ar0 = (0 * 16 + lrow) * LDA;
    const int ar1 = (1 * 16 + lrow) * LDA;
    const int ar2 = (2 * 16 + lrow) * LDA;
    const size_t bc0 = (size_t)(n0w + lrow) * 256;
    const size_t bc1 = (size_t)(n0w + 16 + lrow) * 256;

    f32x4 acc[3][2] = {};
    #pragma unroll
    for (int hb = 0; hb < 2; ++hb) {
        half8 B[8];                            // 2 cols x 4 k-steps
        #pragma unroll
        for (int p = 0; p < 4; ++p) {
            const int ko = (hb * 4 + p) * 32 + kgrp * 8;
            B[2 * p + 0] = *(const half8*)(Th + bc0 + ko);
            B[2 * p + 1] = *(const half8*)(Th + bc1 + ko);
        }
        #pragma unroll
        for (int p = 0; p < 4; ++p) {
            const int ko = (hb * 4 + p) * 32 + kgrp * 8;
            const half8 a0 = *(const half8*)&Crd[ar0 + ko];
            const half8 a1 = *(const half8*)&Crd[ar1 + ko];
            const half8 a2 = *(const half8*)&Crd[ar2 + ko];
            const half8 b0 = B[2 * p + 0], b1 = B[2 * p + 1];
            __builtin_amdgcn_s_setprio(1);
            acc[0][0] = MFMA16(a0, b0, acc[0][0]);
            acc[1][0] = MFMA16(a1, b0, acc[1][0]);
            acc[2][0] = MFMA16(a2, b0, acc[2][0]);
            acc[0][1] = MFMA16(a0, b1, acc[0][1]);
            acc[1][1] = MFMA16(a1, b1, acc[1][1]);
            acc[2][1] = MFMA16(a2, b1, acc[2][1]);
            __builtin_amdgcn_s_setprio(0);
        }
    }
    // writes go to the OTHER arena: no read hazard, single barrier after
    #pragma unroll
    for (int fn = 0; fn < 2; ++fn) {
        const int col = n0w + fn * 16 + lrow;
        #pragma unroll
        for (int fm = 0; fm < 3; ++fm) {
            #pragma unroll
            for (int r = 0; r < 4; ++r) {
                const int row = fm * 16 + kgrp * 4 + r;
                Cwr[row * LDA + col] = (half_t)(acc[fm][fn][r] * gpre[fn][r]);
            }
        }
    }
    __syncthreads();
}

// ---------------- fully fused forward+backward ----------------
__global__ __launch_bounds__(512, 4)
void netgrad_fused(const float* __restrict__ x,
                   const half_t* __restrict__ W1h, const float* __restrict__ b1,
                   const half_t* __restrict__ W2h, const float* __restrict__ b2,
                   const half_t* __restrict__ W3h, const float* __restrict__ b3,
                   const half_t* __restrict__ W4h, const float* __restrict__ b4,
                   const float* __restrict__ W5,
                   const half_t* __restrict__ T4h, const half_t* __restrict__ T3h,
                   const half_t* __restrict__ T2h, const half_t* __restrict__ T1h,
                   float* __restrict__ out)
{
    __shared__ half_t CA[48 * LDA];        // arena A
    __shared__ half_t CB[48 * LDA];        // arena B
    half_t* Hb0 = CA;                      // fwd ping: rows 0-15 of A
    half_t* Hb1 = CA + 16 * LDA;           // fwd pong: rows 16-31 of A
    const int tid = threadIdx.x;
    const int m0s = blockIdx.x * 16;       // sample base

    // ---- load x [16][64] (f16) into Hb0 ----
    if (tid < 256) {
        const int row = tid >> 4, c4 = (tid & 15) * 4;
        const float4 v = *(const float4*)(x + (size_t)(m0s + row) * 64 + c4);
        Hb0[row * LDA + c4 + 0] = (half_t)v.x;
        Hb0[row * LDA + c4 + 1] = (half_t)v.y;
        Hb0[row * LDA + c4 + 2] = (half_t)v.z;
        Hb0[row * LDA + c4 + 3] = (half_t)v.w;
    }
    __syncthreads();

    const int lane = tid & 63, lrow = lane & 15, kgrp = lane >> 4;
    const int wave = tid >> 6;
    const int n0w = wave * 32;

    // ---- forward: G_i stay in registers (lane mapping == bwd consumer) ----
    float G1r[2][4], G2r[2][4], G3r[2][4], G4r[2][4];
    fwd_layer< 64, true >(Hb0, Hb1, W1h, b1, G1r, n0w, lrow, kgrp);
    fwd_layer<256, true >(Hb1, Hb0, W2h, b2, G2r, n0w, lrow, kgrp);
    fwd_layer<256, true >(Hb0, Hb1, W3h, b3, G3r, n0w, lrow, kgrp);
    fwd_layer<256, false>(Hb1, nullptr, W4h, b4, G4r, n0w, lrow, kgrp);

    // ---- expand into arena B: CB[o*16+s][k] = W5[o][k] * G4[s][k] ----
    #pragma unroll
    for (int fn = 0; fn < 2; ++fn) {
        const int k = n0w + fn * 16 + lrow;
        float w5v[3];
        #pragma unroll
        for (int o = 0; o < 3; ++o) w5v[o] = W5[o * 256 + k];
        #pragma unroll
        for (int o = 0; o < 3; ++o)
            #pragma unroll
            for (int r = 0; r < 4; ++r) {
                const int s = kgrp * 4 + r;
                CB[(o * 16 + s) * LDA + k] = (half_t)(w5v[o] * G4r[fn][r]);
            }
    }
    __syncthreads();

    // ---- backward chain, arenas ping-pong: B->A->B->A ----
    bwd_mid(CB, CA, T4h, G3r, n0w, lrow, kgrp);
    bwd_mid(CA, CB, T3h, G2r, n0w, lrow, kgrp);
    bwd_mid(CB, CA, T2h, G1r, n0w, lrow, kgrp);

    // ---- final: CA[48][256] @ T1[64][256]^T -> out rows (m0s+s)*3+o ----
    {
        const int fnf  = wave & 3;
        const int colf = fnf * 16 + lrow;
        const size_t bcf = (size_t)colf * 256;
        half8 B[8];
        #pragma unroll
        for (int p = 0; p < 8; ++p)
            B[p] = *(const half8*)(T1h + bcf + p * 32 + kgrp * 8);
        if (wave < 4) {
            f32x4 acc[2] = {};
            #pragma unroll
            for (int p = 0; p < 8; ++p) {
                const int ko = p * 32 + kgrp * 8;
                #pragma unroll
                for (int fm = 0; fm < 2; ++fm) {
                    const half8 ah = *(const half8*)&CA[(fm * 16 + lrow) * LDA + ko];
                    acc[fm] = MFMA16(ah, B[p], acc[fm]);
                }
            }
            #pragma unroll
            for (int fm = 0; fm < 2; ++fm)
                #pragma unroll
                for (int r = 0; r < 4; ++r) {
                    const int s = kgrp * 4 + r;
                    out[((size_t)(m0s + s) * 3 + fm) * 64 + colf] = acc[fm][r];
                }
        } else {
            f32x4 acc = {};
            #pragma unroll
            for (int p = 0; p < 8; ++p) {
                const int ko = p * 32 + kgrp * 8;
                const half8 ah = *(const half8*)&CA[(2 * 16 + lrow) * LDA + ko];
                acc = MFMA16(ah, B[p], acc);
            }
            #pragma unroll
            for (int r = 0; r < 4; ++r) {
                const int s = kgrp * 4 + r;
                out[((size_t)(m0s + s) * 3 + 2) * 64 + colf] = acc[r];
            }
        }
    }
}

extern "C" void kernel_launch(void* const* d_in, const int* in_sizes, int n_in,
                              void* d_out, int out_size, void* d_ws, size_t ws_size,
                              hipStream_t stream)
{
    const float* x  = (const float*)d_in[0];
    const float* W1 = (const float*)d_in[1];
    const float* b1 = (const float*)d_in[2];
    const float* W2 = (const float*)d_in[3];
    const float* b2 = (const float*)d_in[4];
    const float* W3 = (const float*)d_in[5];
    const float* b3 = (const float*)d_in[6];
    const float* W4 = (const float*)d_in[7];
    const float* b4 = (const float*)d_in[8];
    const float* W5 = (const float*)d_in[9];

    // ---- workspace carve (~1.3 MB: f16-hi weight tables only) ----
    char* p = (char*)d_ws;
    half_t* W1h = (half_t*)p; p += 256 * 64 * 2;
    half_t* T1h = (half_t*)p; p += 64 * 256 * 2;
    half_t* W2h = (half_t*)p; p += 256 * 256 * 2;
    half_t* T2h = (half_t*)p; p += 256 * 256 * 2;
    half_t* W3h = (half_t*)p; p += 256 * 256 * 2;
    half_t* T3h = (half_t*)p; p += 256 * 256 * 2;
    half_t* W4h = (half_t*)p; p += 256 * 256 * 2;
    half_t* T4h = (half_t*)p; p += 256 * 256 * 2;

    prep_split<<<208, 256, 0, stream>>>(W1, W2, W3, W4,
        W1h, T1h, W2h, T2h, W3h, T3h, W4h, T4h);

    netgrad_fused<<<Bsz / 16, 512, 0, stream>>>(x,
        W1h, b1,  W2h, b2,  W3h, b3,  W4h, b4,
        W5,  T4h, T3h, T2h, T1h,
        (float*)d_out);
}

// Round 11
// 59.151 us; speedup vs baseline: 1.9620x; 1.0385x over previous
//
#include <hip/hip_runtime.h>
#include <cstdint>
#include <cstddef>

// NetGrad J = W5 D4 W4 D3 W3 D2 W2 D1 W1, output [B,3,64].
// Fused per-16-sample block, all-f16 MFMA, LDS-traffic-optimized:
//  - 4 waves x FN=4 (halves cross-wave A-read redundancy vs 8 waves)
//  - chain state stored with PERMUTED columns: logical col j at position
//    p = (j&0xC0) | ((j&15)<<2) | ((j>>4)&3)  -> epilogue writes are
//    contiguous half4 (ds_write_b64) and bank-conflict-free.
//    Weight tables pre-permuted along k to match (MFMA contracts by
//    position, so a global k-bijection is exact).
//  - layer-1 A operand loaded straight from x into registers (no staging).

typedef _Float16 half_t;
typedef __attribute__((ext_vector_type(4))) _Float16 half4;
typedef __attribute__((ext_vector_type(8))) _Float16 half8;
typedef __attribute__((ext_vector_type(4))) float f32x4;

#define MFMA16(a, b, c) __builtin_amdgcn_mfma_f32_16x16x32_f16(a, b, c, 0, 0, 0)

constexpr int Bsz = 8192;
constexpr int LDA = 264;          // LDS row stride in halves (528 B)

// logical k held at storage position p (self-describing bijection on 0..255)
__device__ __forceinline__ int kofp(int p) {
    return (p & 0xC0) | ((p & 3) << 4) | ((p >> 2) & 15);
}

// ---------------- prep: gather-permute all weight tables to f16 ----------------
// W1h [256][64] linear; W2p/W3p/W4p [c][p] = W[c][kofp(p)];
// T1p [j<64][p] = W1[kofp(p)][j]; T2p/T3p/T4p [j][p] = W[kofp(p)][j].
__global__ __launch_bounds__(256)
void prep(const float* __restrict__ W1, const float* __restrict__ W2,
          const float* __restrict__ W3, const float* __restrict__ W4,
          half_t* W1h, half_t* T1p,
          half_t* W2p, half_t* W3p, half_t* W4p,
          half_t* T2p, half_t* T3p, half_t* T4p)
{
    int idx = blockIdx.x * 256 + threadIdx.x;
    if (idx < 16384) { W1h[idx] = (half_t)W1[idx]; return; }
    idx -= 16384;
    if (idx < 16384) {
        const int j = idx >> 8, p = idx & 255;
        T1p[idx] = (half_t)W1[kofp(p) * 64 + j];
        return;
    }
    idx -= 16384;
    if (idx >= 6 * 65536) return;
    const int t = idx >> 16, i = idx & 65535;
    const int c = i >> 8, p = i & 255, k = kofp(p);
    switch (t) {
        case 0: W2p[i] = (half_t)W2[c * 256 + k]; break;
        case 1: W3p[i] = (half_t)W3[c * 256 + k]; break;
        case 2: W4p[i] = (half_t)W4[c * 256 + k]; break;
        case 3: T2p[i] = (half_t)W2[k * 256 + c]; break;
        case 4: T3p[i] = (half_t)W3[k * 256 + c]; break;
        case 5: T4p[i] = (half_t)W4[k * 256 + c]; break;
    }
}

// ---------------- fwd layer (K=256): pre = A @ Wp^T + b; G->regs; H'->Awr ----------------
template<bool WRITE_H>
__device__ __forceinline__
void fwd_layer_p(const half_t* __restrict__ Ard, half_t* __restrict__ Awr,
                 const half_t* __restrict__ Wp, const float* __restrict__ bias,
                 float gout[4][4], int n0w, int lrow, int kgrp, int pbase)
{
    const int arow = lrow * LDA;
    f32x4 acc[4] = {};
    #pragma unroll
    for (int kc = 0; kc < 8; ++kc) {
        const int ko = kc * 32 + kgrp * 8;
        const half8 a = *(const half8*)&Ard[arow + ko];
        #pragma unroll
        for (int fn = 0; fn < 4; ++fn) {
            const half8 b = *(const half8*)(Wp + (size_t)(n0w + fn * 16 + lrow) * 256 + ko);
            acc[fn] = MFMA16(a, b, acc[fn]);
        }
    }
    float hv[4][4];
    #pragma unroll
    for (int fn = 0; fn < 4; ++fn) {
        const float bc = bias[n0w + fn * 16 + lrow];
        #pragma unroll
        for (int r = 0; r < 4; ++r) {
            const float pre = acc[fn][r] + bc;
            float g, h;
            if (pre > 0.f) { g = 1.f; h = pre; }
            else           { g = __expf(pre); h = g - 1.f; }
            gout[fn][r] = g;
            hv[r][fn] = h;
        }
    }
    if constexpr (WRITE_H) {
        #pragma unroll
        for (int r = 0; r < 4; ++r) {
            half4 w = {(half_t)hv[r][0], (half_t)hv[r][1],
                       (half_t)hv[r][2], (half_t)hv[r][3]};
            *(half4*)&Awr[(kgrp * 4 + r) * LDA + pbase] = w;
        }
        __syncthreads();
    }
}

// ---------------- bwd mid step: Cwr = (Crd @ Tp^T) * G ----------------
__device__ __forceinline__
void bwd_mid(const half_t* __restrict__ Crd, half_t* __restrict__ Cwr,
             const half_t* __restrict__ Tp, const float gpre[4][4],
             int n0w, int lrow, int kgrp, int pbase)
{
    const int ar0 = lrow * LDA;
    const int ar1 = (16 + lrow) * LDA;
    const int ar2 = (32 + lrow) * LDA;
    f32x4 acc[3][4] = {};
    #pragma unroll
    for (int kc = 0; kc < 8; ++kc) {
        const int ko = kc * 32 + kgrp * 8;
        half8 b[4];
        #pragma unroll
        for (int fn = 0; fn < 4; ++fn)
            b[fn] = *(const half8*)(Tp + (size_t)(n0w + fn * 16 + lrow) * 256 + ko);
        const half8 a0 = *(const half8*)&Crd[ar0 + ko];
        const half8 a1 = *(const half8*)&Crd[ar1 + ko];
        const half8 a2 = *(const half8*)&Crd[ar2 + ko];
        __builtin_amdgcn_s_setprio(1);
        #pragma unroll
        for (int fn = 0; fn < 4; ++fn) {
            acc[0][fn] = MFMA16(a0, b[fn], acc[0][fn]);
            acc[1][fn] = MFMA16(a1, b[fn], acc[1][fn]);
            acc[2][fn] = MFMA16(a2, b[fn], acc[2][fn]);
        }
        __builtin_amdgcn_s_setprio(0);
    }
    #pragma unroll
    for (int o = 0; o < 3; ++o)
        #pragma unroll
        for (int r = 0; r < 4; ++r) {
            half4 w = {(half_t)(acc[o][0][r] * gpre[0][r]),
                       (half_t)(acc[o][1][r] * gpre[1][r]),
                       (half_t)(acc[o][2][r] * gpre[2][r]),
                       (half_t)(acc[o][3][r] * gpre[3][r])};
            *(half4*)&Cwr[(o * 16 + kgrp * 4 + r) * LDA + pbase] = w;
        }
    __syncthreads();
}

// ---------------- fully fused forward+backward ----------------
__global__ __launch_bounds__(256, 2)
void netgrad_fused(const float* __restrict__ x,
                   const half_t* __restrict__ W1h, const float* __restrict__ b1,
                   const half_t* __restrict__ W2p, const float* __restrict__ b2,
                   const half_t* __restrict__ W3p, const float* __restrict__ b3,
                   const half_t* __restrict__ W4p, const float* __restrict__ b4,
                   const float* __restrict__ W5,
                   const half_t* __restrict__ T4p, const half_t* __restrict__ T3p,
                   const half_t* __restrict__ T2p, const half_t* __restrict__ T1p,
                   float* __restrict__ out)
{
    __shared__ half_t CA[48 * LDA];
    __shared__ half_t CB[48 * LDA];
    const int tid  = threadIdx.x;
    const int m0s  = blockIdx.x * 16;
    const int lane = tid & 63, lrow = lane & 15, kgrp = lane >> 4;
    const int wave = tid >> 6;
    const int n0w  = wave * 64;
    const int pbase = (lrow << 2) | (wave << 6);   // permuted write base

    float G1r[4][4], G2r[4][4], G3r[4][4], G4r[4][4];

    // ---- L1: A straight from x (K=64, logical/linear k; W1h linear) ----
    {
        half8 a[2];
        #pragma unroll
        for (int kc = 0; kc < 2; ++kc) {
            const float* xp = x + (size_t)(m0s + lrow) * 64 + kc * 32 + kgrp * 8;
            const float4 v0 = *(const float4*)xp;
            const float4 v1 = *(const float4*)(xp + 4);
            a[kc][0] = (half_t)v0.x; a[kc][1] = (half_t)v0.y;
            a[kc][2] = (half_t)v0.z; a[kc][3] = (half_t)v0.w;
            a[kc][4] = (half_t)v1.x; a[kc][5] = (half_t)v1.y;
            a[kc][6] = (half_t)v1.z; a[kc][7] = (half_t)v1.w;
        }
        f32x4 acc[4] = {};
        #pragma unroll
        for (int kc = 0; kc < 2; ++kc)
            #pragma unroll
            for (int fn = 0; fn < 4; ++fn) {
                const half8 b = *(const half8*)(W1h + (size_t)(n0w + fn * 16 + lrow) * 64
                                                + kc * 32 + kgrp * 8);
                acc[fn] = MFMA16(a[kc], b, acc[fn]);
            }
        float hv[4][4];
        #pragma unroll
        for (int fn = 0; fn < 4; ++fn) {
            const float bc = b1[n0w + fn * 16 + lrow];
            #pragma unroll
            for (int r = 0; r < 4; ++r) {
                const float pre = acc[fn][r] + bc;
                float g, h;
                if (pre > 0.f) { g = 1.f; h = pre; }
                else           { g = __expf(pre); h = g - 1.f; }
                G1r[fn][r] = g;
                hv[r][fn] = h;
            }
        }
        #pragma unroll
        for (int r = 0; r < 4; ++r) {
            half4 w = {(half_t)hv[r][0], (half_t)hv[r][1],
                       (half_t)hv[r][2], (half_t)hv[r][3]};
            *(half4*)&CA[(kgrp * 4 + r) * LDA + pbase] = w;
        }
        __syncthreads();
    }

    // ---- L2..L4: H ping-pong inside CA (rows 0-15 <-> 16-31) ----
    fwd_layer_p<true >(CA,            CA + 16 * LDA, W2p, b2, G2r, n0w, lrow, kgrp, pbase);
    fwd_layer_p<true >(CA + 16 * LDA, CA,            W3p, b3, G3r, n0w, lrow, kgrp, pbase);
    fwd_layer_p<false>(CA,            nullptr,       W4p, b4, G4r, n0w, lrow, kgrp, pbase);

    // ---- expand into CB: C0[o*16+s][k] = W5[o][k] * G4[s][k] ----
    {
        float w5v[3][4];
        #pragma unroll
        for (int fn = 0; fn < 4; ++fn) {
            const int k = n0w + fn * 16 + lrow;
            #pragma unroll
            for (int o = 0; o < 3; ++o) w5v[o][fn] = W5[o * 256 + k];
        }
        #pragma unroll
        for (int o = 0; o < 3; ++o)
            #pragma unroll
            for (int r = 0; r < 4; ++r) {
                half4 w = {(half_t)(w5v[o][0] * G4r[0][r]),
                           (half_t)(w5v[o][1] * G4r[1][r]),
                           (half_t)(w5v[o][2] * G4r[2][r]),
                           (half_t)(w5v[o][3] * G4r[3][r])};
                *(half4*)&CB[(o * 16 + kgrp * 4 + r) * LDA + pbase] = w;
            }
        __syncthreads();
    }

    // ---- backward chain: CB -> CA -> CB -> CA ----
    bwd_mid(CB, CA, T4p, G3r, n0w, lrow, kgrp, pbase);
    bwd_mid(CA, CB, T3p, G2r, n0w, lrow, kgrp, pbase);
    bwd_mid(CB, CA, T2p, G1r, n0w, lrow, kgrp, pbase);

    // ---- final: CA[48][256] @ T1p^T -> out; 4 waves x 16 cols each ----
    {
        const int j = wave * 16 + lrow;
        const size_t bcf = (size_t)j * 256;
        f32x4 acc[3] = {};
        #pragma unroll
        for (int kc = 0; kc < 8; ++kc) {
            const int ko = kc * 32 + kgrp * 8;
            const half8 b = *(const half8*)(T1p + bcf + ko);
            acc[0] = MFMA16(*(const half8*)&CA[lrow * LDA + ko],        b, acc[0]);
            acc[1] = MFMA16(*(const half8*)&CA[(16 + lrow) * LDA + ko], b, acc[1]);
            acc[2] = MFMA16(*(const half8*)&CA[(32 + lrow) * LDA + ko], b, acc[2]);
        }
        #pragma unroll
        for (int o = 0; o < 3; ++o)
            #pragma unroll
            for (int r = 0; r < 4; ++r)
                out[((size_t)(m0s + kgrp * 4 + r) * 3 + o) * 64 + j] = acc[o][r];
    }
}

extern "C" void kernel_launch(void* const* d_in, const int* in_sizes, int n_in,
                              void* d_out, int out_size, void* d_ws, size_t ws_size,
                              hipStream_t stream)
{
    const float* x  = (const float*)d_in[0];
    const float* W1 = (const float*)d_in[1];
    const float* b1 = (const float*)d_in[2];
    const float* W2 = (const float*)d_in[3];
    const float* b2 = (const float*)d_in[4];
    const float* W3 = (const float*)d_in[5];
    const float* b3 = (const float*)d_in[6];
    const float* W4 = (const float*)d_in[7];
    const float* b4 = (const float*)d_in[8];
    const float* W5 = (const float*)d_in[9];

    // ---- workspace carve (~0.9 MB f16 tables) ----
    char* p = (char*)d_ws;
    half_t* W1h = (half_t*)p; p += 256 * 64 * 2;
    half_t* T1p = (half_t*)p; p += 64 * 256 * 2;
    half_t* W2p = (half_t*)p; p += 256 * 256 * 2;
    half_t* W3p = (half_t*)p; p += 256 * 256 * 2;
    half_t* W4p = (half_t*)p; p += 256 * 256 * 2;
    half_t* T2p = (half_t*)p; p += 256 * 256 * 2;
    half_t* T3p = (half_t*)p; p += 256 * 256 * 2;
    half_t* T4p = (half_t*)p; p += 256 * 256 * 2;

    const int prep_elems = 16384 + 16384 + 6 * 65536;
    prep<<<(prep_elems + 255) / 256, 256, 0, stream>>>(W1, W2, W3, W4,
        W1h, T1p, W2p, W3p, W4p, T2p, T3p, T4p);

    netgrad_fused<<<Bsz / 16, 256, 0, stream>>>(x,
        W1h, b1,  W2p, b2,  W3p, b3,  W4p, b4,
        W5,  T4p, T3p, T2p, T1p,
        (float*)d_out);
}